// Round 1
// baseline (426.423 us; speedup 1.0000x reference)
//
#include <hip/hip_runtime.h>
#include <hip/hip_bf16.h>
#include <math.h>

#define NB 2
#define LL 64
#define NMESH 100000
#define HEADS_O 8
#define DHC 64
#define DMODEL 512
#define DINNER 1024
#define DSTATE 64
#define NH 16
#define CONVDIM 1152
#define DINPROJ 2208
#define DOUT 256

typedef __attribute__((ext_vector_type(8))) short short8v;   // 8 x bf16
typedef __attribute__((ext_vector_type(4))) float f32x4;
typedef __attribute__((ext_vector_type(8))) unsigned short ushort8v;

__device__ __forceinline__ unsigned short f2bf(float f) {
  union { float f; unsigned u; } v; v.f = f;
  unsigned u = v.u;
  u += 0x7FFFu + ((u >> 16) & 1u);
  return (unsigned short)(u >> 16);
}

// ---------------------------------------------------------------- K1: in_proj
// zxbcdt[b,l,o] = sum_m u[b,l,m] * in_proj_w[o,m];  u[b,l,h*64+c]=slice_token[b,h,l,c]
__global__ void k_inproj(const float* __restrict__ st, const float* __restrict__ w,
                         float* __restrict__ zx) {
  int bl = blockIdx.x;            // b*64 + l
  int b = bl >> 6, l = bl & 63;
  __shared__ float u[DMODEL];
  int t = threadIdx.x;
  for (int m = t; m < DMODEL; m += 256) {
    int h = m >> 6, c = m & 63;
    u[m] = st[((size_t)(b*HEADS_O + h)*LL + l)*DHC + c];
  }
  __syncthreads();
  int o = blockIdx.y * 256 + t;
  if (o < DINPROJ) {
    const float4* wr = (const float4*)(w + (size_t)o * DMODEL);
    float acc = 0.f;
    #pragma unroll 4
    for (int m4 = 0; m4 < DMODEL/4; ++m4) {
      float4 wv = wr[m4];
      const float* up = &u[m4*4];
      acc += wv.x*up[0] + wv.y*up[1] + wv.z*up[2] + wv.w*up[3];
    }
    zx[(size_t)bl * DINPROJ + o] = acc;
  }
}

// ---------------------------------------------------------------- K2: dt
// dtbuf[s,l,h] = softplus(dt_raw + bias); s<2 fwd (ch h), s>=2 bwd (ch 16+h, time-flip)
__global__ void k_dt(const float* __restrict__ zx, const float* __restrict__ dtb,
                     float* __restrict__ dtbuf) {
  int i = blockIdx.x*256 + threadIdx.x;          // (s*64+l)*16+h, 4096 total
  if (i >= 4*LL*NH) return;
  int h = i & 15, l = (i >> 4) & 63, s = i >> 10;
  float v;
  if (s < 2)
    v = zx[(size_t)(s*LL + l)*DINPROJ + (DINNER + CONVDIM) + h];
  else
    v = zx[(size_t)((s-2)*LL + (63-l))*DINPROJ + (DINNER + CONVDIM) + 16 + h];
  v += dtb[h];
  dtbuf[i] = (v > 20.f) ? v : log1pf(expf(v));
}

// ---------------------------------------------------------------- K3: depthwise conv + silu
__global__ void k_conv(const float* __restrict__ zx, const float* __restrict__ cw,
                       const float* __restrict__ cb, float* __restrict__ conv_out) {
  int i = blockIdx.x*256 + threadIdx.x;
  if (i >= NB*LL*CONVDIM) return;
  int c = i % CONVDIM; int l = (i / CONVDIM) % LL; int b = i / (CONVDIM*LL);
  float s = cb[c];
  #pragma unroll
  for (int k = 0; k < 3; ++k) {
    int tt = l - 1 + k;
    if (tt >= 0 && tt < LL)
      s += cw[c*3 + k] * zx[(size_t)(b*LL + tt)*DINPROJ + DINNER + c];
  }
  conv_out[i] = s / (1.f + expf(-s));
}

// ---------------------------------------------------------------- K4: SSD scan (parallel form)
// y[s,t,h,p] = sum_{ta<=t} exp(A*(D[t]-D[ta])) * (B_ta . C_t) * dt_ta * x_ta[p]
__global__ void k_scan(const float* __restrict__ conv_out, const float* __restrict__ dtbuf,
                       const float* __restrict__ A_log, float* __restrict__ ybuf) {
  int blk = blockIdx.x;
  int s = blk >> 4, hh = blk & 15;
  int b = s & 1;
  bool rev = (s >= 2);
  int t = threadIdx.x;
  int wv = t >> 6, lane = t & 63;
  __shared__ float Bs[64*68];
  __shared__ float Cs[64*68];
  __shared__ float Xs[64*64];
  __shared__ float dts[64];
  __shared__ float Dc[64];

  for (int id = t; id < 4096; id += 256) {
    int tt0 = id >> 6, n = id & 63;
    int tt = rev ? (63 - tt0) : tt0;
    size_t base = (size_t)(b*LL + tt) * CONVDIM;
    Xs[tt0*64 + n] = conv_out[base + hh*64 + n];
    Bs[tt0*68 + n] = conv_out[base + DINNER + n];
    Cs[tt0*68 + n] = conv_out[base + DINNER + DSTATE + n];
  }
  if (t < 64) dts[t] = dtbuf[(size_t)(s*LL + t)*NH + hh];
  __syncthreads();
  if (t < 64) {
    float v = dts[t];
    #pragma unroll
    for (int m = 1; m < 64; m <<= 1) {
      float o = __shfl_up(v, m, 64);
      if (lane >= m) v += o;
    }
    Dc[t] = v;
  }
  __syncthreads();
  float A = -expf(A_log[hh]);
  float g[16];
  #pragma unroll
  for (int i = 0; i < 16; ++i) {
    int tt = wv + 4*i;      // wave-uniform row
    int ta = lane;
    float gv = 0.f;
    if (ta <= tt) {
      const float* Br = &Bs[ta*68];
      const float* Cr = &Cs[tt*68];
      float dot = 0.f;
      #pragma unroll
      for (int n4 = 0; n4 < 16; ++n4) {
        float4 bv = *(const float4*)&Br[n4*4];
        float4 cv = *(const float4*)&Cr[n4*4];
        dot += bv.x*cv.x + bv.y*cv.y + bv.z*cv.z + bv.w*cv.w;
      }
      gv = dot * expf(A * (Dc[tt] - Dc[ta])) * dts[ta];
    }
    g[i] = gv;
  }
  __syncthreads();
  #pragma unroll
  for (int i = 0; i < 16; ++i) Bs[(wv + 4*i)*64 + lane] = g[i];   // reuse Bs as G
  __syncthreads();
  for (int id = t; id < 4096; id += 256) {
    int tt = id >> 6, p = id & 63;
    float y = 0.f;
    for (int ta = 0; ta <= tt; ++ta) y += Bs[tt*64 + ta] * Xs[ta*64 + p];
    ybuf[(size_t)(s*LL + tt)*DINNER + hh*64 + p] = y;
  }
}

// ---------------------------------------------------------------- K5: combine + gate + RMSnorm + out_proj
__global__ void k_combine(const float* __restrict__ conv_out, const float* __restrict__ zx,
                          const float* __restrict__ yb, const float* __restrict__ fcD,
                          const float* __restrict__ Dd, const float* __restrict__ nw,
                          const float* __restrict__ opw, float* __restrict__ oh) {
  int bl = blockIdx.x; int b = bl >> 6, l = bl & 63;
  int t = threadIdx.x;
  __shared__ float xog[DINNER];
  __shared__ float yrow[DINNER];
  __shared__ float diag[NH];
  __shared__ float wsum[4];
  size_t base = (size_t)bl * CONVDIM;
  for (int c = t; c < DINNER; c += 256) xog[c] = conv_out[base + c];
  __syncthreads();
  {
    int hh = t >> 4, j = t & 15;
    const float* fr = fcD + (size_t)hh*DINNER;
    float acc = 0.f;
    for (int k = 0; k < 64; ++k) acc += xog[j + 16*k] * fr[j + 16*k];
    #pragma unroll
    for (int m = 8; m >= 1; m >>= 1) acc += __shfl_xor(acc, m, 64);
    if (j == 0) diag[hh] = acc + Dd[hh];
  }
  __syncthreads();
  float ss = 0.f;
  float y2v[4];
  #pragma unroll
  for (int i = 0; i < 4; ++i) {
    int c = t + 256*i;
    float yf = (l == 0)  ? 0.f : yb[(size_t)(b*LL + l - 1)*DINNER + c];
    float yw = (l == 63) ? 0.f : yb[(size_t)((2+b)*LL + 62 - l)*DINNER + c];
    float y1 = yf + yw + xog[c]*diag[c >> 6];
    float z = zx[(size_t)bl*DINPROJ + c];
    float y2 = y1 * (z / (1.f + expf(-z)));
    y2v[i] = y2;
    ss += y2*y2;
  }
  #pragma unroll
  for (int m = 32; m >= 1; m >>= 1) ss += __shfl_xor(ss, m, 64);
  if ((t & 63) == 0) wsum[t >> 6] = ss;
  __syncthreads();
  float tot = wsum[0] + wsum[1] + wsum[2] + wsum[3];
  float scale = rsqrtf(tot * (1.f/1024.f) + 1e-5f);
  #pragma unroll
  for (int i = 0; i < 4; ++i) {
    int c = t + 256*i;
    yrow[c] = y2v[i] * scale * nw[c];
  }
  __syncthreads();
  for (int m = t; m < DMODEL; m += 256) {
    const float4* wr = (const float4*)(opw + (size_t)m*DINNER);
    float acc = 0.f;
    #pragma unroll 4
    for (int c4 = 0; c4 < DINNER/4; ++c4) {
      float4 wv = wr[c4];
      const float* yp = &yrow[c4*4];
      acc += wv.x*yp[0] + wv.y*yp[1] + wv.z*yp[2] + wv.w*yp[3];
    }
    oh[(size_t)bl*DMODEL + m] = acc;
  }
}

// ---------------------------------------------------------------- K6: build M in B-fragment order (bf16)
// M[b,h,g,d] = sum_c oh[b,g,h*64+c] * tow[d,h*64+c]
// frag layout: mf[((((b*8+h)*2+kk)*16+ct)*64+lane)*8+j], g=kk*32+8*(lane>>4)+j, d=ct*16+(lane&15)
__global__ void k_mfrag(const float* __restrict__ oh, const float* __restrict__ tow,
                        unsigned short* __restrict__ mf) {
  int bg = blockIdx.x; int b = bg >> 6, g = bg & 63;
  int t = threadIdx.x;
  __shared__ float orow[DMODEL];
  for (int m = t; m < DMODEL; m += 256) orow[m] = oh[(size_t)bg*DMODEL + m];
  __syncthreads();
  for (int idx = t; idx < HEADS_O*DOUT; idx += 256) {
    int h = idx >> 8, d = idx & 255;
    const float* wr = tow + (size_t)d*DMODEL + h*64;
    const float* yp = &orow[h*64];
    float acc = 0.f;
    #pragma unroll
    for (int c4 = 0; c4 < 16; ++c4) {
      float4 wv = *(const float4*)&wr[c4*4];
      acc += wv.x*yp[c4*4] + wv.y*yp[c4*4+1] + wv.z*yp[c4*4+2] + wv.w*yp[c4*4+3];
    }
    int kk = g >> 5;
    int lane = (d & 15) | (((g & 31) >> 3) << 4);
    int j = g & 7;
    size_t off = ((((size_t)(b*HEADS_O + h)*2 + kk)*16 + (d >> 4))*64 + lane)*8 + j;
    mf[off] = f2bf(acc);
  }
}

// ---------------------------------------------------------------- K7: the big fused GEMM
// out[b,n,d] = sum_{h,g} W[b,h,n,g]*M[b,h,g,d] + tob[d]
__global__ __launch_bounds__(256) void k_out_gemm(const float* __restrict__ W,
                                                  const unsigned short* __restrict__ mf,
                                                  const float* __restrict__ tob,
                                                  float* __restrict__ out) {
  int b = blockIdx.y;
  int n0 = blockIdx.x * 64;
  int tid = threadIdx.x;
  int wv = tid >> 6, lane = tid & 63;
  __shared__ __align__(16) unsigned short lsB[2][8192];   // 16KB each
  f32x4 acc[16];
  #pragma unroll
  for (int i = 0; i < 16; ++i) acc[i] = (f32x4){0.f,0.f,0.f,0.f};

  int row = n0 + wv*16 + (lane & 15);
  int rowc = row < NMESH ? row : 0;
  int kgrp = lane >> 4;

  // stage step 0
  {
    const unsigned short* src = mf + (size_t)(b*HEADS_O + 0)*2*8192;
    #pragma unroll
    for (int i = 0; i < 4; ++i) {
      int e = tid + 256*i;
      *(ushort8v*)&lsB[0][e*8] = *(const ushort8v*)&src[e*8];
    }
  }
  for (int s = 0; s < 16; ++s) {
    __syncthreads();
    int h = s >> 1, kk = s & 1;
    const float* ap = W + ((size_t)(b*HEADS_O + h)*NMESH + rowc)*64 + kk*32 + kgrp*8;
    float4 a0 = *(const float4*)ap;
    float4 a1 = *(const float4*)(ap + 4);
    short8v af;
    af[0] = (short)f2bf(a0.x); af[1] = (short)f2bf(a0.y);
    af[2] = (short)f2bf(a0.z); af[3] = (short)f2bf(a0.w);
    af[4] = (short)f2bf(a1.x); af[5] = (short)f2bf(a1.y);
    af[6] = (short)f2bf(a1.z); af[7] = (short)f2bf(a1.w);
    const unsigned short* lb = &lsB[s & 1][0];
    #pragma unroll
    for (int ct = 0; ct < 16; ++ct) {
      short8v bf = *(const short8v*)&lb[ct*512 + lane*8];
      acc[ct] = __builtin_amdgcn_mfma_f32_16x16x32_bf16(af, bf, acc[ct], 0, 0, 0);
    }
    if (s < 15) {
      int s2 = s + 1;
      const unsigned short* src = mf + ((size_t)(b*HEADS_O + (s2 >> 1))*2 + (s2 & 1))*8192;
      unsigned short* dst = &lsB[s2 & 1][0];
      #pragma unroll
      for (int i = 0; i < 4; ++i) {
        int e = tid + 256*i;
        *(ushort8v*)&dst[e*8] = *(const ushort8v*)&src[e*8];
      }
    }
  }
  // epilogue
  int col = lane & 15;
  int rbase = n0 + wv*16 + ((lane >> 4) << 2);
  #pragma unroll
  for (int ct = 0; ct < 16; ++ct) {
    float bias = tob[ct*16 + col];
    #pragma unroll
    for (int r = 0; r < 4; ++r) {
      int rr = rbase + r;
      if (rr < NMESH)
        out[((size_t)b*NMESH + rr)*DOUT + ct*16 + col] = acc[ct][r] + bias;
    }
  }
}

// ----------------------------------------------------------------
extern "C" void kernel_launch(void* const* d_in, const int* in_sizes, int n_in,
                              void* d_out, int out_size, void* d_ws, size_t ws_size,
                              hipStream_t stream) {
  (void)in_sizes; (void)n_in; (void)out_size; (void)ws_size;
  const float* st   = (const float*)d_in[0];
  const float* sw   = (const float*)d_in[1];
  const float* ipw  = (const float*)d_in[2];
  const float* cw   = (const float*)d_in[3];
  const float* cb   = (const float*)d_in[4];
  const float* dtb  = (const float*)d_in[5];
  const float* alog = (const float*)d_in[6];
  const float* fcD  = (const float*)d_in[7];
  const float* Dd   = (const float*)d_in[8];
  const float* nw   = (const float*)d_in[9];
  const float* opw  = (const float*)d_in[10];
  const float* tow  = (const float*)d_in[11];
  const float* tob  = (const float*)d_in[12];
  float* out = (float*)d_out;
  unsigned char* ws = (unsigned char*)d_ws;

  float* zx   = (float*)(ws + 0);            // 2*64*2208*4   = 1130496
  float* conv = (float*)(ws + 1130496);      // 2*64*1152*4   = 589824
  float* dtp  = (float*)(ws + 1720320);      // 4*64*16*4     = 16384
  float* yb   = (float*)(ws + 1736704);      // 4*64*1024*4   = 1048576
  float* oh   = (float*)(ws + 2785280);      // 2*64*512*4    = 262144
  unsigned short* mfr = (unsigned short*)(ws + 3047424); // 2*8*2*16*64*8*2 = 524288

  k_inproj <<<dim3(128, 9), 256, 0, stream>>>(st, ipw, zx);
  k_dt     <<<16,  256, 0, stream>>>(zx, dtb, dtp);
  k_conv   <<<576, 256, 0, stream>>>(zx, cw, cb, conv);
  k_scan   <<<64,  256, 0, stream>>>(conv, dtp, alog, yb);
  k_combine<<<128, 256, 0, stream>>>(conv, zx, yb, fcD, Dd, nw, opw, oh);
  k_mfrag  <<<128, 256, 0, stream>>>(oh, tow, mfr);
  k_out_gemm<<<dim3((NMESH + 63)/64, NB), 256, 0, stream>>>(sw, mfr, tob, out);
}

// Round 2
// 334.409 us; speedup vs baseline: 1.2752x; 1.2752x over previous
//
#include <hip/hip_runtime.h>
#include <hip/hip_bf16.h>
#include <math.h>

#define NB 2
#define LL 64
#define NMESH 100000
#define HEADS_O 8
#define DHC 64
#define DMODEL 512
#define DINNER 1024
#define DSTATE 64
#define NH 16
#define CONVDIM 1152
#define DINPROJ 2208
#define DOUT 256

typedef __attribute__((ext_vector_type(8))) short short8v;   // 8 x bf16
typedef __attribute__((ext_vector_type(4))) float f32x4;

__device__ __forceinline__ unsigned short f2bf(float f) {
  union { float f; unsigned u; } v; v.f = f;
  unsigned u = v.u;
  u += 0x7FFFu + ((u >> 16) & 1u);
  return (unsigned short)(u >> 16);
}

__device__ __forceinline__ float dot4(float4 a, const float* b) {
  return a.x*b[0] + a.y*b[1] + a.z*b[2] + a.w*b[3];
}

// ---------------------------------------------------------------- K1: in_proj (weight-streaming)
// zx[bl,o] = sum_m u[bl,m] * w[o,m]; u rows staged in LDS, broadcast to all lanes.
__global__ void k_inproj(const float* __restrict__ st, const float* __restrict__ w,
                         float* __restrict__ zx) {
  int oc = blockIdx.x;             // 0..8 : o = oc*256 + t
  int blc = blockIdx.y;            // 0..15: bl = blc*8 + r
  int t = threadIdx.x;
  __shared__ float u[8][DMODEL];   // 16 KB
  for (int idx = t; idx < 8*DMODEL; idx += 256) {
    int r = idx >> 9, m = idx & 511;
    int bl = blc*8 + r; int b = bl >> 6, l = bl & 63;
    u[r][m] = st[((size_t)(b*HEADS_O + (m >> 6))*LL + l)*DHC + (m & 63)];
  }
  __syncthreads();
  int o = oc*256 + t;
  if (o < DINPROJ) {
    const float4* wr = (const float4*)(w + (size_t)o*DMODEL);
    float acc[8] = {0,0,0,0,0,0,0,0};
    for (int m4 = 0; m4 < DMODEL/4; ++m4) {
      float4 wv = wr[m4];
      #pragma unroll
      for (int r = 0; r < 8; ++r) acc[r] += dot4(wv, &u[r][m4*4]);
    }
    #pragma unroll
    for (int r = 0; r < 8; ++r)
      zx[(size_t)(blc*8 + r)*DINPROJ + o] = acc[r];
  }
}

// ---------------------------------------------------------------- K2: dt
__global__ void k_dt(const float* __restrict__ zx, const float* __restrict__ dtb,
                     float* __restrict__ dtbuf) {
  int i = blockIdx.x*256 + threadIdx.x;          // (s*64+l)*16+h, 4096 total
  if (i >= 4*LL*NH) return;
  int h = i & 15, l = (i >> 4) & 63, s = i >> 10;
  float v;
  if (s < 2)
    v = zx[(size_t)(s*LL + l)*DINPROJ + (DINNER + CONVDIM) + h];
  else
    v = zx[(size_t)((s-2)*LL + (63-l))*DINPROJ + (DINNER + CONVDIM) + 16 + h];
  v += dtb[h];
  dtbuf[i] = (v > 20.f) ? v : log1pf(expf(v));
}

// ---------------------------------------------------------------- K3: depthwise conv + silu
__global__ void k_conv(const float* __restrict__ zx, const float* __restrict__ cw,
                       const float* __restrict__ cb, float* __restrict__ conv_out) {
  int i = blockIdx.x*256 + threadIdx.x;
  if (i >= NB*LL*CONVDIM) return;
  int c = i % CONVDIM; int l = (i / CONVDIM) % LL; int b = i / (CONVDIM*LL);
  float s = cb[c];
  #pragma unroll
  for (int k = 0; k < 3; ++k) {
    int tt = l - 1 + k;
    if (tt >= 0 && tt < LL)
      s += cw[c*3 + k] * zx[(size_t)(b*LL + tt)*DINPROJ + DINNER + c];
  }
  conv_out[i] = s / (1.f + expf(-s));
}

// ---------------------------------------------------------------- K4: SSD scan (parallel form)
__global__ void k_scan(const float* __restrict__ conv_out, const float* __restrict__ dtbuf,
                       const float* __restrict__ A_log, float* __restrict__ ybuf) {
  int blk = blockIdx.x;
  int s = blk >> 4, hh = blk & 15;
  int b = s & 1;
  bool rev = (s >= 2);
  int t = threadIdx.x;
  int wv = t >> 6, lane = t & 63;
  __shared__ float Bs[64*68];
  __shared__ float Cs[64*68];
  __shared__ float Xs[64*64];
  __shared__ float dts[64];
  __shared__ float Dc[64];

  for (int id = t; id < 4096; id += 256) {
    int tt0 = id >> 6, n = id & 63;
    int tt = rev ? (63 - tt0) : tt0;
    size_t base = (size_t)(b*LL + tt) * CONVDIM;
    Xs[tt0*64 + n] = conv_out[base + hh*64 + n];
    Bs[tt0*68 + n] = conv_out[base + DINNER + n];
    Cs[tt0*68 + n] = conv_out[base + DINNER + DSTATE + n];
  }
  if (t < 64) dts[t] = dtbuf[(size_t)(s*LL + t)*NH + hh];
  __syncthreads();
  if (t < 64) {
    float v = dts[t];
    #pragma unroll
    for (int m = 1; m < 64; m <<= 1) {
      float o = __shfl_up(v, m, 64);
      if (lane >= m) v += o;
    }
    Dc[t] = v;
  }
  __syncthreads();
  float A = -expf(A_log[hh]);
  float g[16];
  #pragma unroll
  for (int i = 0; i < 16; ++i) {
    int tt = wv + 4*i;
    int ta = lane;
    float gv = 0.f;
    if (ta <= tt) {
      const float* Br = &Bs[ta*68];
      const float* Cr = &Cs[tt*68];
      float dot = 0.f;
      #pragma unroll
      for (int n4 = 0; n4 < 16; ++n4) {
        float4 bv = *(const float4*)&Br[n4*4];
        float4 cv = *(const float4*)&Cr[n4*4];
        dot += bv.x*cv.x + bv.y*cv.y + bv.z*cv.z + bv.w*cv.w;
      }
      gv = dot * expf(A * (Dc[tt] - Dc[ta])) * dts[ta];
    }
    g[i] = gv;
  }
  __syncthreads();
  #pragma unroll
  for (int i = 0; i < 16; ++i) Bs[(wv + 4*i)*64 + lane] = g[i];
  __syncthreads();
  for (int id = t; id < 4096; id += 256) {
    int tt = id >> 6, p = id & 63;
    float y = 0.f;
    for (int ta = 0; ta <= tt; ++ta) y += Bs[tt*64 + ta] * Xs[ta*64 + p];
    ybuf[(size_t)(s*LL + tt)*DINNER + hh*64 + p] = y;
  }
}

// ---------------------------------------------------------------- K5a: combine + gate + RMSnorm -> ynorm
__global__ void k_combine_a(const float* __restrict__ conv_out, const float* __restrict__ zx,
                            const float* __restrict__ yb, const float* __restrict__ fcD,
                            const float* __restrict__ Dd, const float* __restrict__ nw,
                            float* __restrict__ ynorm) {
  int bl = blockIdx.x; int b = bl >> 6, l = bl & 63;
  int t = threadIdx.x;
  __shared__ float xog[DINNER];
  __shared__ float diag[NH];
  __shared__ float wsum[4];
  size_t base = (size_t)bl * CONVDIM;
  for (int c = t; c < DINNER; c += 256) xog[c] = conv_out[base + c];
  __syncthreads();
  {
    int hh = t >> 4, j = t & 15;
    const float* fr = fcD + (size_t)hh*DINNER;
    float acc = 0.f;
    for (int k = 0; k < 64; ++k) acc += xog[j + 16*k] * fr[j + 16*k];
    #pragma unroll
    for (int m = 8; m >= 1; m >>= 1) acc += __shfl_xor(acc, m, 64);
    if (j == 0) diag[hh] = acc + Dd[hh];
  }
  __syncthreads();
  float ss = 0.f;
  float y2v[4];
  #pragma unroll
  for (int i = 0; i < 4; ++i) {
    int c = t + 256*i;
    float yf = (l == 0)  ? 0.f : yb[(size_t)(b*LL + l - 1)*DINNER + c];
    float yw = (l == 63) ? 0.f : yb[(size_t)((2+b)*LL + 62 - l)*DINNER + c];
    float y1 = yf + yw + xog[c]*diag[c >> 6];
    float z = zx[(size_t)bl*DINPROJ + c];
    float y2 = y1 * (z / (1.f + expf(-z)));
    y2v[i] = y2;
    ss += y2*y2;
  }
  #pragma unroll
  for (int m = 32; m >= 1; m >>= 1) ss += __shfl_xor(ss, m, 64);
  if ((t & 63) == 0) wsum[t >> 6] = ss;
  __syncthreads();
  float tot = wsum[0] + wsum[1] + wsum[2] + wsum[3];
  float scale = rsqrtf(tot * (1.f/1024.f) + 1e-5f);
  #pragma unroll
  for (int i = 0; i < 4; ++i) {
    int c = t + 256*i;
    ynorm[(size_t)bl*DINNER + c] = y2v[i] * scale * nw[c];
  }
}

// ---------------------------------------------------------------- K5b: out_proj (weight-streaming)
// oh[bl,o] = sum_k ynorm[bl,k] * opw[o,k]
__global__ void k_oproj(const float* __restrict__ ynorm, const float* __restrict__ opw,
                        float* __restrict__ oh) {
  int oc = blockIdx.x;            // 0..1 : o = oc*256 + t
  int blc = blockIdx.y;           // 0..31: bl = blc*4 + r
  int t = threadIdx.x;
  __shared__ float yr[4][DINNER]; // 16 KB
  for (int idx = t; idx < 4*DINNER; idx += 256) {
    int r = idx >> 10, k = idx & 1023;
    yr[r][k] = ynorm[(size_t)(blc*4 + r)*DINNER + k];
  }
  __syncthreads();
  int o = oc*256 + t;
  const float4* wr = (const float4*)(opw + (size_t)o*DINNER);
  float acc[4] = {0,0,0,0};
  for (int k4 = 0; k4 < DINNER/4; ++k4) {
    float4 wv = wr[k4];
    #pragma unroll
    for (int r = 0; r < 4; ++r) acc[r] += dot4(wv, &yr[r][k4*4]);
  }
  #pragma unroll
  for (int r = 0; r < 4; ++r)
    oh[(size_t)(blc*4 + r)*DMODEL + o] = acc[r];
}

// ---------------------------------------------------------------- K6: build M in B-fragment order (bf16)
// M[b,h,g,d] = sum_c oh[b,g,h*64+c] * tow[d,h*64+c]
__global__ void k_mfrag(const float* __restrict__ oh, const float* __restrict__ tow,
                        unsigned short* __restrict__ mfp) {
  int bgc = blockIdx.x;            // 0..15, bg = bgc*8 + r
  int t = threadIdx.x;
  __shared__ float orow[8][DMODEL]; // 16 KB
  for (int idx = t; idx < 8*DMODEL; idx += 256) {
    int r = idx >> 9, m = idx & 511;
    orow[r][m] = oh[(size_t)(bgc*8 + r)*DMODEL + m];
  }
  __syncthreads();
  #pragma unroll
  for (int ii = 0; ii < 8; ++ii) {
    int idx = t + 256*ii;          // 0..2047 -> (h,d)
    int h = idx >> 8, d = idx & 255;
    const float4* wr = (const float4*)(tow + (size_t)d*DMODEL + h*64);
    float acc[8] = {0,0,0,0,0,0,0,0};
    #pragma unroll
    for (int c4 = 0; c4 < 16; ++c4) {
      float4 wv = wr[c4];
      #pragma unroll
      for (int r = 0; r < 8; ++r) acc[r] += dot4(wv, &orow[r][h*64 + c4*4]);
    }
    #pragma unroll
    for (int r = 0; r < 8; ++r) {
      int bg = bgc*8 + r; int b = bg >> 6, g = bg & 63;
      int kk = g >> 5;
      int ln = (d & 15) | (((g & 31) >> 3) << 4);
      int j = g & 7;
      mfp[((((size_t)(b*HEADS_O + h)*2 + kk)*16 + (d >> 4))*64 + ln)*8 + j] = f2bf(acc[r]);
    }
  }
}

// ---------------------------------------------------------------- K7: big fused GEMM, pipelined
// out[b,n,d] = sum_{h,g} W[b,h,n,g]*M[b,h,g,d] + tob[d]
#define GLDS(g, l) __builtin_amdgcn_global_load_lds( \
    (const __attribute__((address_space(1))) void*)(g), \
    (__attribute__((address_space(3))) void*)(l), 16, 0, 0)

__global__ __launch_bounds__(256, 2) void k_out_gemm(const float* __restrict__ W,
                                                     const unsigned short* __restrict__ mf,
                                                     const float* __restrict__ tob,
                                                     float* __restrict__ out) {
  int b = blockIdx.y;
  int n0 = blockIdx.x * 128;
  int tid = threadIdx.x;
  int wv = tid >> 6, lane = tid & 63;
  __shared__ __align__(16) unsigned short lsB[2][8192];   // 16 KB x2

  f32x4 acc0[16], acc1[16];
  #pragma unroll
  for (int i = 0; i < 16; ++i) { acc0[i] = (f32x4){0,0,0,0}; acc1[i] = (f32x4){0,0,0,0}; }

  int r0 = n0 + wv*32 + (lane & 15);
  int r1 = r0 + 16;
  int rc0 = r0 < NMESH ? r0 : NMESH-1;
  int rc1 = r1 < NMESH ? r1 : NMESH-1;
  int kgrp = lane >> 4;
  const float* base0 = W + (size_t)b*HEADS_O*NMESH*64 + (size_t)rc0*64 + kgrp*8;
  const float* base1 = W + (size_t)b*HEADS_O*NMESH*64 + (size_t)rc1*64 + kgrp*8;
  const unsigned short* mfb = mf + (size_t)b*16*8192 + tid*8;

  float4 a0n, a1n, a2n, a3n;

  // ---- prologue: stage s=0, prefetch A(0)
  {
    unsigned short* dst = &lsB[0][tid*8];
    #pragma unroll
    for (int i = 0; i < 4; ++i) GLDS(mfb + i*2048, dst + i*2048);
    asm volatile("" ::: "memory");
    a0n = *(const float4*)base0; a1n = *(const float4*)(base0 + 4);
    a2n = *(const float4*)base1; a3n = *(const float4*)(base1 + 4);
    asm volatile("s_waitcnt vmcnt(4)" ::: "memory");
    __builtin_amdgcn_s_barrier();
    asm volatile("" ::: "memory");
  }

  #pragma unroll
  for (int s = 0; s < 16; ++s) {
    const int buf = s & 1;
    if (s < 15) {   // stage s+1 into other buffer
      const unsigned short* src = mfb + (size_t)(s+1)*8192;
      unsigned short* dst = &lsB[buf ^ 1][tid*8];
      #pragma unroll
      for (int i = 0; i < 4; ++i) GLDS(src + i*2048, dst + i*2048);
      asm volatile("" ::: "memory");
    }
    // convert current A (compiler auto-waits the right vmcnt)
    short8v af0, af1;
    af0[0] = (short)f2bf(a0n.x); af0[1] = (short)f2bf(a0n.y);
    af0[2] = (short)f2bf(a0n.z); af0[3] = (short)f2bf(a0n.w);
    af0[4] = (short)f2bf(a1n.x); af0[5] = (short)f2bf(a1n.y);
    af0[6] = (short)f2bf(a1n.z); af0[7] = (short)f2bf(a1n.w);
    af1[0] = (short)f2bf(a2n.x); af1[1] = (short)f2bf(a2n.y);
    af1[2] = (short)f2bf(a2n.z); af1[3] = (short)f2bf(a2n.w);
    af1[4] = (short)f2bf(a3n.x); af1[5] = (short)f2bf(a3n.y);
    af1[6] = (short)f2bf(a3n.z); af1[7] = (short)f2bf(a3n.w);
    if (s < 15) {   // prefetch A(s+1)
      int s2 = s + 1; int h = s2 >> 1, kk = s2 & 1;
      const float* p0 = base0 + (size_t)h*NMESH*64 + kk*32;
      const float* p1 = base1 + (size_t)h*NMESH*64 + kk*32;
      a0n = *(const float4*)p0; a1n = *(const float4*)(p0 + 4);
      a2n = *(const float4*)p1; a3n = *(const float4*)(p1 + 4);
      asm volatile("" ::: "memory");
    }
    const unsigned short* lb = &lsB[buf][lane*8];
    #pragma unroll
    for (int ct = 0; ct < 16; ++ct) {
      short8v bf = *(const short8v*)(lb + ct*512);
      acc0[ct] = __builtin_amdgcn_mfma_f32_16x16x32_bf16(af0, bf, acc0[ct], 0, 0, 0);
      acc1[ct] = __builtin_amdgcn_mfma_f32_16x16x32_bf16(af1, bf, acc1[ct], 0, 0, 0);
    }
    if (s < 15) {
      // staging (4 oldest vmem ops) must land; A-prefetch (4 newest) stays in flight
      asm volatile("s_waitcnt vmcnt(4) lgkmcnt(0)" ::: "memory");
      __builtin_amdgcn_s_barrier();
      asm volatile("" ::: "memory");
    }
  }

  // ---- epilogue
  int col = lane & 15;
  int rb0 = n0 + wv*32 + ((lane >> 4) << 2);
  int rb1 = rb0 + 16;
  bool full = (n0 + 128 <= NMESH);
  #pragma unroll
  for (int ct = 0; ct < 16; ++ct) {
    float bias = tob[ct*16 + col];
    if (full) {
      #pragma unroll
      for (int r = 0; r < 4; ++r) {
        out[((size_t)b*NMESH + rb0 + r)*DOUT + ct*16 + col] = acc0[ct][r] + bias;
        out[((size_t)b*NMESH + rb1 + r)*DOUT + ct*16 + col] = acc1[ct][r] + bias;
      }
    } else {
      #pragma unroll
      for (int r = 0; r < 4; ++r) {
        if (rb0 + r < NMESH)
          out[((size_t)b*NMESH + rb0 + r)*DOUT + ct*16 + col] = acc0[ct][r] + bias;
        if (rb1 + r < NMESH)
          out[((size_t)b*NMESH + rb1 + r)*DOUT + ct*16 + col] = acc1[ct][r] + bias;
      }
    }
  }
}

// ----------------------------------------------------------------
extern "C" void kernel_launch(void* const* d_in, const int* in_sizes, int n_in,
                              void* d_out, int out_size, void* d_ws, size_t ws_size,
                              hipStream_t stream) {
  (void)in_sizes; (void)n_in; (void)out_size; (void)ws_size;
  const float* st   = (const float*)d_in[0];
  const float* sw   = (const float*)d_in[1];
  const float* ipw  = (const float*)d_in[2];
  const float* cw   = (const float*)d_in[3];
  const float* cb   = (const float*)d_in[4];
  const float* dtb  = (const float*)d_in[5];
  const float* alog = (const float*)d_in[6];
  const float* fcD  = (const float*)d_in[7];
  const float* Dd   = (const float*)d_in[8];
  const float* nw   = (const float*)d_in[9];
  const float* opw  = (const float*)d_in[10];
  const float* tow  = (const float*)d_in[11];
  const float* tob  = (const float*)d_in[12];
  float* out = (float*)d_out;
  unsigned char* ws = (unsigned char*)d_ws;

  float* zx   = (float*)(ws + 0);            // 2*64*2208*4   = 1130496
  float* conv = (float*)(ws + 1130496);      // 2*64*1152*4   = 589824
  float* dtp  = (float*)(ws + 1720320);      // 4*64*16*4     = 16384
  float* yb   = (float*)(ws + 1736704);      // 4*64*1024*4   = 1048576
  float* oh   = (float*)(ws + 2785280);      // 2*64*512*4    = 262144
  unsigned short* mfr = (unsigned short*)(ws + 3047424); // 524288
  float* ynm  = (float*)(ws + 3571712);      // 2*64*1024*4   = 524288

  k_inproj   <<<dim3(9, 16), 256, 0, stream>>>(st, ipw, zx);
  k_dt       <<<16,  256, 0, stream>>>(zx, dtb, dtp);
  k_conv     <<<576, 256, 0, stream>>>(zx, cw, cb, conv);
  k_scan     <<<64,  256, 0, stream>>>(conv, dtp, alog, yb);
  k_combine_a<<<128, 256, 0, stream>>>(conv, zx, yb, fcD, Dd, nw, ynm);
  k_oproj    <<<dim3(2, 32), 256, 0, stream>>>(ynm, opw, oh);
  k_mfrag    <<<16,  256, 0, stream>>>(oh, tow, mfr);
  k_out_gemm <<<dim3((NMESH + 127)/128, NB), 256, 0, stream>>>(sw, mfr, tob, out);
}